// Round 4
// baseline (15496.924 us; speedup 1.0000x reference)
//
#include <hip/hip_runtime.h>
#include <hip/hip_bf16.h>
#include <stdint.h>

#define SEQ   2048
#define EMB   256
#define HHD   256      // per-direction hidden
#define GATES 1024     // 4*HHD
#define NTAGS 12
#define START 10
#define STOP  11
#define CCH   16       // CRF chunks
#define CLEN  128      // steps per chunk

__device__ __forceinline__ int sdot4(uint32_t a, uint32_t b, int c) {
#if __has_builtin(__builtin_amdgcn_sdot4)
  return __builtin_amdgcn_sdot4((int)a, (int)b, c, false);
#else
  int r = c;
#pragma unroll
  for (int i = 0; i < 4; i++) {
    int av = (int)(signed char)((a >> (8 * i)) & 255);
    int bv = (int)(signed char)((b >> (8 * i)) & 255);
    r += av * bv;
  }
  return r;
#endif
}

__device__ __forceinline__ float fsig(float x) {
  float e = __expf(-x);
  return __builtin_amdgcn_rcpf(1.0f + e);
}

// ---------------- 1. fused: Whh->int8 quant (blocks 512..1023) + input projection ----
// proj writes pre[] GATE-INTERLEAVED: slot(t, row r) = (r&255)*4 + qmap[r>>8]
// quad order in k_lstm: pos0=i, pos1=g, pos2=f, pos3=o  ->  qmap(i,f,g,o) = {0,2,1,3}
__global__ __launch_bounds__(256) void k_prep(const int* __restrict__ sentence,
                                              const float* __restrict__ embed,
                                              const float* __restrict__ Wih_f,
                                              const float* __restrict__ bih_f,
                                              const float* __restrict__ bhh_f,
                                              const float* __restrict__ Wih_b,
                                              const float* __restrict__ bih_b,
                                              const float* __restrict__ bhh_b,
                                              const float* __restrict__ whh_f,
                                              const float* __restrict__ whh_b,
                                              uint32_t* __restrict__ q4,
                                              float* __restrict__ scales,
                                              float* __restrict__ pre) {
  const int tid = threadIdx.x;
  if (blockIdx.x >= 512) {
    // ---- quant part ----
    const int idx  = (blockIdx.x - 512) * 256 + tid;
    const int row  = idx >> 6;          // 0..2047
    const int lane = tid & 63;
    const int d = row >> 10, r = row & 1023;
    const float4 w = *(const float4*)((d ? whh_b : whh_f) + (long)r * HHD + lane * 4);
    float m = fmaxf(fmaxf(fabsf(w.x), fabsf(w.y)), fmaxf(fabsf(w.z), fabsf(w.w)));
#pragma unroll
    for (int off = 32; off; off >>= 1) m = fmaxf(m, __shfl_xor(m, off, 64));
    m = fmaxf(m, 1e-20f);
    const float inv = 127.f / m;
    int a = (int)rintf(w.x * inv), b = (int)rintf(w.y * inv);
    int c = (int)rintf(w.z * inv), e = (int)rintf(w.w * inv);
    q4[row * 64 + lane] = (uint32_t)(a & 255) | ((uint32_t)(b & 255) << 8) |
                          ((uint32_t)(c & 255) << 16) | ((uint32_t)(e & 255) << 24);
    if (lane == 0) scales[row] = m / 127.f;
    return;
  }
  // ---- proj part ----
  const int dir = blockIdx.x >> 8;
  const int t0  = (blockIdx.x & 255) * 8;
  const float* Wih = dir ? Wih_b : Wih_f;
  const float* bih = dir ? bih_b : bih_f;
  const float* bhh = dir ? bhh_b : bhh_f;

  __shared__ float xs[8][256];
#pragma unroll
  for (int i = 0; i < 8; i++) {
    int s = sentence[t0 + i];
    xs[i][tid] = embed[(long)s * EMB + tid];
  }
  __syncthreads();

  const int r0 = tid * 4;
  float acc[4][8];
#pragma unroll
  for (int j = 0; j < 4; j++)
#pragma unroll
    for (int t = 0; t < 8; t++) acc[j][t] = 0.f;

  const float4* W4 = (const float4*)Wih;
  for (int kq = 0; kq < 64; kq++) {
    float4 w[4];
#pragma unroll
    for (int j = 0; j < 4; j++) w[j] = W4[(r0 + j) * 64 + kq];
#pragma unroll
    for (int t = 0; t < 8; t++) {
      float4 xv = ((const float4*)xs[t])[kq];
#pragma unroll
      for (int j = 0; j < 4; j++)
        acc[j][t] += w[j].x * xv.x + w[j].y * xv.y + w[j].z * xv.z + w[j].w * xv.w;
    }
  }
  const int glin = r0 >> 8;                              // gate index (i,f,g,o)
  const int qpos = (glin == 0) ? 0 : (glin == 1) ? 2 : (glin == 2) ? 1 : 3;
#pragma unroll
  for (int j = 0; j < 4; j++) {
    const int u = (r0 + j) & 255;
    float bsum = bih[r0 + j] + bhh[r0 + j];
#pragma unroll
    for (int t = 0; t < 8; t++)
      pre[((long)(dir * SEQ + t0 + t)) * GATES + u * 4 + qpos] = acc[j][t] + bsum;
  }
}

// ---------------- 2. sequential LSTM: 1 block/dir, 1024 thr, 1 gate-row per lane -----
// Lane L = 4u+g owns row {i:u, g:512+u, f:256+u, o:768+u}[g]. 64 weight dwords/lane
// fit the 128-VGPR arch budget at 4 waves/SIMD -> no AGPR shuttling.
__global__ __launch_bounds__(1024) void k_lstm(const uint32_t* __restrict__ q4,
                                               const float* __restrict__ scales,
                                               const float* __restrict__ pre,
                                               const float* __restrict__ h0,
                                               const float* __restrict__ c0,
                                               float* __restrict__ hs) {
  const int dir = blockIdx.x;
  const int L   = threadIdx.x;
  const int u   = L >> 2;
  const int g   = L & 3;

  __shared__ __align__(16) uint8_t hbuf[2][256];

  const int gbase = (g == 0) ? 0 : (g == 1) ? 512 : (g == 2) ? 256 : 768;
  const int row   = gbase + u;
  const long base = (long)dir * GATES;

  uint4 w[16];
  {
    const uint4* qq = (const uint4*)q4;
#pragma unroll
    for (int j = 0; j < 16; j++) w[j] = qq[(base + row) * 16 + j];
  }
  const float sc = scales[base + row];

  if (L < 256) {
    float v = h0[dir * HHD + L] * (127.f / 4.f);
    v = fminf(fmaxf(v, -127.f), 127.f);
    hbuf[0][L] = (uint8_t)(int)rintf(v);
  }
  float c_st = c0[dir * HHD + u];
  __syncthreads();

  const float* pd = pre + (long)dir * SEQ * GATES;
  float* hsd      = hs  + (long)dir * SEQ * HHD;

  const long dlt = dir ? -(long)GATES : (long)GATES;
  const float* pp = pd + (long)(dir ? SEQ - 1 : 0) * GATES + L;
  float nxt = *pp;

  const float gm  = (g == 1) ? 2.f : 1.f;   // tanh(x)=2*sig(2x)-1 for the g-gate
  const bool  is2 = (g & 2) != 0;           // lanes 2,3 hold f,o
  const bool  is3 = (g == 3);

  for (int s = 0; s < SEQ; s++) {
    const int t = dir ? (SEQ - 1 - s) : s;
    const float pre_v = nxt;
    if (s + 1 < SEQ) pp += dlt;
    nxt = *pp;                                // prefetch next step under the dots

    const uint4* hq4 = (const uint4*)hbuf[s & 1];
    int acc = 0;
#pragma unroll 4
    for (int cc = 0; cc < 16; cc++) {
      uint4 hq = hq4[cc];
      acc = sdot4(w[cc].x, hq.x, acc);
      acc = sdot4(w[cc].y, hq.y, acc);
      acc = sdot4(w[cc].z, hq.z, acc);
      acc = sdot4(w[cc].w, hq.w, acc);
    }
    const float hsc = (s == 0) ? (4.f / 127.f) : (1.f / 127.f);
    const float gv  = pre_v + sc * hsc * (float)acc;

    // activation: sig for i,f,o ; tanh for g (gm trick, divergence-free)
    const float x = fsig(gv * gm) * gm - (gm - 1.f);
    const float y = __shfl_xor(x, 1, 64);     // quad: 0<->1 (i,g), 2<->3 (f,o)
    // products: lanes 0,1 -> i*g ; lanes 2,3 -> f*c
    const float a = is2 ? c_st : y;
    const float b = is3 ? y : x;
    const float q = b * a;
    const float z = __shfl_xor(q, 2, 64);
    const float c_new = q + z;                // identical on all 4 quad lanes
    c_st = c_new;

    const float th = 2.f * fsig(2.f * c_new) - 1.f;
    const float ho = is3 ? x : y;             // o on lanes 2,3
    const float hv = ho * th;

    if (g == 2) hbuf[(s + 1) & 1][u] = (uint8_t)(int)rintf(hv * 127.f);  // |hv|<1
    if (g == 3) hsd[(long)t * HHD + u] = hv;
    __syncthreads();
  }
}

// ---------------- 3. CRF chunk: compute feats for 128 steps, fold to 12x12, gold -----
__global__ __launch_bounds__(192) void k_crf_chunk(const float* __restrict__ hs,
                                                   const float* __restrict__ W_out,
                                                   const float* __restrict__ b_out,
                                                   const float* __restrict__ trans,
                                                   const int* __restrict__ tags,
                                                   float* __restrict__ Pc,
                                                   float* __restrict__ Pg) {
  const int ch  = blockIdx.x;
  const int tid = threadIdx.x;

  __shared__ float Wl[12 * 520];
  __shared__ float fe[CLEN * NTAGS];
  for (int i = tid; i < 12 * 512; i += 192) Wl[(i / 512) * 520 + (i % 512)] = W_out[i];
  __syncthreads();

  // feats: 16 t-slots x 12 tags; each thread does 8 timesteps
  {
    const int slot = tid / 12, n = tid % 12;
    const float bn = b_out[n];
    const float4* Wa = (const float4*)&Wl[n * 520];
    const float4* Wb = (const float4*)&Wl[n * 520 + 256];
    for (int k = 0; k < 8; k++) {
      const int tl = k * 16 + slot;
      const int t  = ch * CLEN + tl;
      const float4* hf4 = (const float4*)(hs + (long)t * HHD);
      const float4* hb4 = (const float4*)(hs + (long)SEQ * HHD + (long)t * HHD);
      float acc = bn;
#pragma unroll 8
      for (int j = 0; j < 64; j++) {
        float4 w = Wa[j], h = hf4[j];
        acc += w.x * h.x + w.y * h.y + w.z * h.z + w.w * h.w;
      }
#pragma unroll 8
      for (int j = 0; j < 64; j++) {
        float4 w = Wb[j], h = hb4[j];
        acc += w.x * h.x + w.y * h.y + w.z * h.z + w.w * h.w;
      }
      fe[tl * NTAGS + n] = acc;
    }
  }
  __syncthreads();

  // fold 128 steps into a 12x12 log-semiring matrix
  {
    const int n  = tid & 15;
    const int p  = tid >> 4;
    const int nn = (n < 12) ? n : 11;
    float trn[12];
#pragma unroll
    for (int j = 0; j < 12; j++) trn[j] = trans[nn * 12 + j];

    float Mv = trans[nn * 12 + p] + fe[nn];
    for (int t = 1; t < CLEN; t++) {
      float x[12], m = -1e30f;
#pragma unroll
      for (int j = 0; j < 12; j++) {
        x[j] = trn[j] + __shfl(Mv, (tid & 48) | j, 64);
        m = fmaxf(m, x[j]);
      }
      float ss = 0.f;
#pragma unroll
      for (int j = 0; j < 12; j++) ss += __expf(x[j] - m);
      Mv = fe[t * NTAGS + nn] + m + __logf(ss);
    }
    if (n < 12) Pc[ch * 144 + n * 12 + p] = Mv;
  }

  // partial gold score for this chunk (fe is read-only now)
  if (tid < 64) {
    float gp = 0.f;
#pragma unroll
    for (int b = 0; b < 2; b++) {
      const int tl = b * 64 + tid;
      const int t  = ch * CLEN + tl;
      const int tg = tags[t];
      const int pv = (t == 0) ? START : tags[t - 1];
      gp += trans[tg * 12 + pv] + fe[tl * NTAGS + tg];
    }
#pragma unroll
    for (int off = 32; off; off >>= 1) gp += __shfl_xor(gp, off, 64);
    if (tid == 0) Pg[ch] = gp;
  }
}

// ---------------- 4. combine chunk matrices + stop + gold -----------------------------
__global__ __launch_bounds__(64) void k_crf_final(const float* __restrict__ Pc,
                                                  const float* __restrict__ Pg,
                                                  const int* __restrict__ tags,
                                                  const float* __restrict__ trans,
                                                  float* __restrict__ out) {
  const int tid = threadIdx.x;
  const int nn  = (tid < 12) ? tid : 11;

  float fv = (tid == START) ? 0.f : -10000.f;
  for (int c = 0; c < CCH; c++) {
    float x[12], m = -1e30f;
#pragma unroll
    for (int j = 0; j < 12; j++) {
      x[j] = Pc[c * 144 + nn * 12 + j] + __shfl(fv, j, 64);
      m = fmaxf(m, x[j]);
    }
    float ss = 0.f;
#pragma unroll
    for (int j = 0; j < 12; j++) ss += __expf(x[j] - m);
    fv = m + __logf(ss);
  }
  const float v = fv + trans[STOP * 12 + nn];
  float xs[12], m = -1e30f;
#pragma unroll
  for (int j = 0; j < 12; j++) {
    xs[j] = __shfl(v, j, 64);
    m = fmaxf(m, xs[j]);
  }
  float ss = 0.f;
#pragma unroll
  for (int j = 0; j < 12; j++) ss += __expf(xs[j] - m);
  const float fwd = m + __logf(ss);

  float gp = (tid < CCH) ? Pg[tid] : 0.f;
#pragma unroll
  for (int off = 32; off; off >>= 1) gp += __shfl_xor(gp, off, 64);

  if (tid == 0) out[0] = fwd - (gp + trans[STOP * 12 + tags[SEQ - 1]]);
}

// -------------------------------------------------------------------------------------
extern "C" void kernel_launch(void* const* d_in, const int* in_sizes, int n_in,
                              void* d_out, int out_size, void* d_ws, size_t ws_size,
                              hipStream_t stream) {
  const int*   sentence = (const int*)  d_in[0];
  const int*   tags     = (const int*)  d_in[1];
  const float* embed    = (const float*)d_in[2];
  const float* Wih_f    = (const float*)d_in[3];
  const float* Whh_f    = (const float*)d_in[4];
  const float* bih_f    = (const float*)d_in[5];
  const float* bhh_f    = (const float*)d_in[6];
  const float* Wih_b    = (const float*)d_in[7];
  const float* Whh_b    = (const float*)d_in[8];
  const float* bih_b    = (const float*)d_in[9];
  const float* bhh_b    = (const float*)d_in[10];
  const float* W_out    = (const float*)d_in[11];
  const float* b_out    = (const float*)d_in[12];
  const float* h0       = (const float*)d_in[13];
  const float* c0       = (const float*)d_in[14];
  const float* trans    = (const float*)d_in[15];
  float* out = (float*)d_out;

  char* ws = (char*)d_ws;
  uint32_t* q4    = (uint32_t*)ws;                          // 512 KB
  float*    scales= (float*)(ws + (512l << 10));            // 8 KB
  float*    pre   = (float*)(ws + (1l  << 20));             // 16 MB : pre[2][2048][1024] interleaved
  float*    hs    = (float*)(ws + (17l << 20));             // 4 MB  : hs[2][2048][256]
  float*    Pc    = (float*)(ws + (21l << 20));             // 9 KB  : Pc[16][12][12]
  float*    Pg    = (float*)(ws + (21l << 20) + (16l<<10)); // 64 B  : Pg[16]

  k_prep<<<1024, 256, 0, stream>>>(sentence, embed, Wih_f, bih_f, bhh_f,
                                   Wih_b, bih_b, bhh_b, Whh_f, Whh_b,
                                   q4, scales, pre);
  k_lstm<<<2, 1024, 0, stream>>>(q4, scales, pre, h0, c0, hs);
  k_crf_chunk<<<CCH, 192, 0, stream>>>(hs, W_out, b_out, trans, tags, Pc, Pg);
  k_crf_final<<<1, 64, 0, stream>>>(Pc, Pg, tags, trans, out);
}

// Round 5
// 2284.390 us; speedup vs baseline: 6.7838x; 6.7838x over previous
//
#include <hip/hip_runtime.h>
#include <hip/hip_bf16.h>
#include <stdint.h>

#define SEQ   2048
#define EMB   256
#define HHD   256      // per-direction hidden
#define GATES 1024     // 4*HHD
#define NTAGS 12
#define START 10
#define STOP  11
#define CCH   16       // CRF chunks
#define CLEN  128      // steps per chunk

__device__ __forceinline__ int sdot4(uint32_t a, uint32_t b, int c) {
#if __has_builtin(__builtin_amdgcn_sdot4)
  return __builtin_amdgcn_sdot4((int)a, (int)b, c, false);
#else
  int r = c;
#pragma unroll
  for (int i = 0; i < 4; i++) {
    int av = (int)(signed char)((a >> (8 * i)) & 255);
    int bv = (int)(signed char)((b >> (8 * i)) & 255);
    r += av * bv;
  }
  return r;
#endif
}

__device__ __forceinline__ float fsig(float x) {
  float e = __expf(-x);
  return __builtin_amdgcn_rcpf(1.0f + e);
}

__device__ __forceinline__ void sched_fence() {
#if __has_builtin(__builtin_amdgcn_sched_barrier)
  __builtin_amdgcn_sched_barrier(0);
#endif
}

// ---------------- 1. fused: input projection (blocks 0..255) + Whh quant (256..767) --
// proj writes pre[] GATE-INTERLEAVED: slot(t, row r) = (r&255)*4 + qmap[r>>8]
// quad order in k_lstm: pos0=i, pos1=g, pos2=f, pos3=o  ->  qmap(i,f,g,o) = {0,2,1,3}
__global__ __launch_bounds__(256) void k_prep(const int* __restrict__ sentence,
                                              const float* __restrict__ embed,
                                              const float* __restrict__ Wih_f,
                                              const float* __restrict__ bih_f,
                                              const float* __restrict__ bhh_f,
                                              const float* __restrict__ Wih_b,
                                              const float* __restrict__ bih_b,
                                              const float* __restrict__ bhh_b,
                                              const float* __restrict__ whh_f,
                                              const float* __restrict__ whh_b,
                                              uint32_t* __restrict__ q4,
                                              float* __restrict__ scales,
                                              float* __restrict__ pre) {
  const int tid = threadIdx.x;
  if (blockIdx.x >= 256) {
    // ---- quant part: one wave per gate-row ----
    const int idx  = (blockIdx.x - 256) * 256 + tid;
    const int row  = idx >> 6;          // 0..2047
    const int lane = tid & 63;
    const int d = row >> 10, r = row & 1023;
    const float4 w = *(const float4*)((d ? whh_b : whh_f) + (long)r * HHD + lane * 4);
    float m = fmaxf(fmaxf(fabsf(w.x), fabsf(w.y)), fmaxf(fabsf(w.z), fabsf(w.w)));
#pragma unroll
    for (int off = 32; off; off >>= 1) m = fmaxf(m, __shfl_xor(m, off, 64));
    m = fmaxf(m, 1e-20f);
    const float inv = 127.f / m;
    int a = (int)rintf(w.x * inv), b = (int)rintf(w.y * inv);
    int c = (int)rintf(w.z * inv), e = (int)rintf(w.w * inv);
    q4[row * 64 + lane] = (uint32_t)(a & 255) | ((uint32_t)(b & 255) << 8) |
                          ((uint32_t)(c & 255) << 16) | ((uint32_t)(e & 255) << 24);
    if (lane == 0) scales[row] = m / 127.f;
    return;
  }
  // ---- proj part: 16 timesteps per block ----
  const int dir = blockIdx.x >> 7;
  const int t0  = (blockIdx.x & 127) * 16;
  const float* Wih = dir ? Wih_b : Wih_f;
  const float* bih = dir ? bih_b : bih_f;
  const float* bhh = dir ? bhh_b : bhh_f;

  __shared__ float xs[16][256];
#pragma unroll
  for (int i = 0; i < 16; i++) {
    int s = sentence[t0 + i];
    xs[i][tid] = embed[(long)s * EMB + tid];
  }
  __syncthreads();

  const int r0 = tid * 4;
  float acc[4][16];
#pragma unroll
  for (int j = 0; j < 4; j++)
#pragma unroll
    for (int t = 0; t < 16; t++) acc[j][t] = 0.f;

  const float4* W4 = (const float4*)Wih;
  for (int kq = 0; kq < 64; kq++) {
    float4 w[4];
#pragma unroll
    for (int j = 0; j < 4; j++) w[j] = W4[(r0 + j) * 64 + kq];
#pragma unroll
    for (int t = 0; t < 16; t++) {
      float4 xv = ((const float4*)xs[t])[kq];
#pragma unroll
      for (int j = 0; j < 4; j++)
        acc[j][t] += w[j].x * xv.x + w[j].y * xv.y + w[j].z * xv.z + w[j].w * xv.w;
    }
  }
  const int glin = r0 >> 8;                              // gate index (i,f,g,o)
  const int qpos = (glin == 0) ? 0 : (glin == 1) ? 2 : (glin == 2) ? 1 : 3;
#pragma unroll
  for (int j = 0; j < 4; j++) {
    const int u = (r0 + j) & 255;
    float bsum = bih[r0 + j] + bhh[r0 + j];
#pragma unroll
    for (int t = 0; t < 16; t++)
      pre[((long)(dir * SEQ + t0 + t)) * GATES + u * 4 + qpos] = acc[j][t] + bsum;
  }
}

// ---------------- 2. sequential LSTM: 1 block/dir, 1024 thr, 1 gate-row per lane -----
// Lane L = 4u+g owns row {i:u, g:512+u, f:256+u, o:768+u}[g]. 64 weight dwords/lane,
// FULLY-UNROLLED static indexing (dynamic indexing => scratch, the R4 bug).
// ~105 VGPR demand < 128-arch cap at 4 waves/SIMD -> no AGPR shuttling, no spill.
__global__ __launch_bounds__(1024) void k_lstm(const uint32_t* __restrict__ q4,
                                               const float* __restrict__ scales,
                                               const float* __restrict__ pre,
                                               const float* __restrict__ h0,
                                               const float* __restrict__ c0,
                                               float* __restrict__ hs) {
  const int dir = blockIdx.x;
  const int L   = threadIdx.x;
  const int u   = L >> 2;
  const int g   = L & 3;

  __shared__ __align__(16) uint8_t hbuf[2][256];

  const int gbase = (g == 0) ? 0 : (g == 1) ? 512 : (g == 2) ? 256 : 768;
  const int row   = gbase + u;
  const long base = (long)dir * GATES;

  uint4 w[16];
  {
    const uint4* qq = (const uint4*)q4;
#pragma unroll
    for (int j = 0; j < 16; j++) w[j] = qq[(base + row) * 16 + j];
  }
  const float sc = scales[base + row];

  if (L < 256) {
    float v = h0[dir * HHD + L] * (127.f / 4.f);
    v = fminf(fmaxf(v, -127.f), 127.f);
    hbuf[0][L] = (uint8_t)(int)rintf(v);
  }
  float c_st = c0[dir * HHD + u];
  __syncthreads();

  const float* pd = pre + (long)dir * SEQ * GATES;
  float* hsd      = hs  + (long)dir * SEQ * HHD;

  const long dlt = dir ? -(long)GATES : (long)GATES;
  const float* pp = pd + (long)(dir ? SEQ - 1 : 0) * GATES + L;
  float nxt = *pp;

  const float gm  = (g == 1) ? 2.f : 1.f;   // tanh(x)=2*sig(2x)-1 for the g-gate
  const bool  is2 = (g & 2) != 0;           // lanes 2,3 hold f,o
  const bool  is3 = (g == 3);

  for (int s = 0; s < SEQ; s++) {
    const int t = dir ? (SEQ - 1 - s) : s;
    const float pre_v = nxt;
    if (s + 1 < SEQ) pp += dlt;
    nxt = *pp;                                // prefetch next step under the dots

    const uint4* hq4 = (const uint4*)hbuf[s & 1];
    int acc = 0;
    // 4 groups of (4 x ds_read_b128 -> 16 x sdot4); sched_barrier between groups
    // caps in-flight h registers so total pressure stays under the 128 cap.
#pragma unroll
    for (int blk = 0; blk < 4; blk++) {
      uint4 h0q = hq4[blk * 4 + 0];
      uint4 h1q = hq4[blk * 4 + 1];
      uint4 h2q = hq4[blk * 4 + 2];
      uint4 h3q = hq4[blk * 4 + 3];
      acc = sdot4(w[blk * 4 + 0].x, h0q.x, acc);
      acc = sdot4(w[blk * 4 + 0].y, h0q.y, acc);
      acc = sdot4(w[blk * 4 + 0].z, h0q.z, acc);
      acc = sdot4(w[blk * 4 + 0].w, h0q.w, acc);
      acc = sdot4(w[blk * 4 + 1].x, h1q.x, acc);
      acc = sdot4(w[blk * 4 + 1].y, h1q.y, acc);
      acc = sdot4(w[blk * 4 + 1].z, h1q.z, acc);
      acc = sdot4(w[blk * 4 + 1].w, h1q.w, acc);
      acc = sdot4(w[blk * 4 + 2].x, h2q.x, acc);
      acc = sdot4(w[blk * 4 + 2].y, h2q.y, acc);
      acc = sdot4(w[blk * 4 + 2].z, h2q.z, acc);
      acc = sdot4(w[blk * 4 + 2].w, h2q.w, acc);
      acc = sdot4(w[blk * 4 + 3].x, h3q.x, acc);
      acc = sdot4(w[blk * 4 + 3].y, h3q.y, acc);
      acc = sdot4(w[blk * 4 + 3].z, h3q.z, acc);
      acc = sdot4(w[blk * 4 + 3].w, h3q.w, acc);
      sched_fence();
    }
    const float hsc = (s == 0) ? (4.f / 127.f) : (1.f / 127.f);
    const float gv  = pre_v + sc * hsc * (float)acc;

    // activation: sig for i,f,o ; tanh for g (gm trick, divergence-free)
    const float x = fsig(gv * gm) * gm - (gm - 1.f);
    const float y = __shfl_xor(x, 1, 64);     // quad: 0<->1 (i,g), 2<->3 (f,o)
    const float a = is2 ? c_st : y;
    const float b = is3 ? y : x;
    const float q = b * a;                    // lanes0,1: i*g ; lanes2,3: f*c
    const float z = __shfl_xor(q, 2, 64);
    const float c_new = q + z;                // identical on all 4 quad lanes
    c_st = c_new;

    const float th = 2.f * fsig(2.f * c_new) - 1.f;
    const float ho = is3 ? x : y;             // o on lanes 2,3
    const float hv = ho * th;

    if (g == 2) hbuf[(s + 1) & 1][u] = (uint8_t)(int)rintf(hv * 127.f);  // |hv|<1
    if (g == 3) hsd[(long)t * HHD + u] = hv;
    __syncthreads();
  }
}

// ---------------- 3. CRF chunk: compute feats for 128 steps, fold to 12x12, gold -----
__global__ __launch_bounds__(192) void k_crf_chunk(const float* __restrict__ hs,
                                                   const float* __restrict__ W_out,
                                                   const float* __restrict__ b_out,
                                                   const float* __restrict__ trans,
                                                   const int* __restrict__ tags,
                                                   float* __restrict__ Pc,
                                                   float* __restrict__ Pg) {
  const int ch  = blockIdx.x;
  const int tid = threadIdx.x;

  __shared__ float Wl[12 * 520];
  __shared__ float fe[CLEN * NTAGS];
  for (int i = tid; i < 12 * 512; i += 192) Wl[(i / 512) * 520 + (i % 512)] = W_out[i];
  __syncthreads();

  // feats: 16 t-slots x 12 tags; each thread does 8 timesteps
  {
    const int slot = tid / 12, n = tid % 12;
    const float bn = b_out[n];
    const float4* Wa = (const float4*)&Wl[n * 520];
    const float4* Wb = (const float4*)&Wl[n * 520 + 256];
    for (int k = 0; k < 8; k++) {
      const int tl = k * 16 + slot;
      const int t  = ch * CLEN + tl;
      const float4* hf4 = (const float4*)(hs + (long)t * HHD);
      const float4* hb4 = (const float4*)(hs + (long)SEQ * HHD + (long)t * HHD);
      float acc = bn;
#pragma unroll 8
      for (int j = 0; j < 64; j++) {
        float4 w = Wa[j], h = hf4[j];
        acc += w.x * h.x + w.y * h.y + w.z * h.z + w.w * h.w;
      }
#pragma unroll 8
      for (int j = 0; j < 64; j++) {
        float4 w = Wb[j], h = hb4[j];
        acc += w.x * h.x + w.y * h.y + w.z * h.z + w.w * h.w;
      }
      fe[tl * NTAGS + n] = acc;
    }
  }
  __syncthreads();

  // fold 128 steps into a 12x12 log-semiring matrix
  {
    const int n  = tid & 15;
    const int p  = tid >> 4;
    const int nn = (n < 12) ? n : 11;
    float trn[12];
#pragma unroll
    for (int j = 0; j < 12; j++) trn[j] = trans[nn * 12 + j];

    float Mv = trans[nn * 12 + p] + fe[nn];
    for (int t = 1; t < CLEN; t++) {
      float x[12], m = -1e30f;
#pragma unroll
      for (int j = 0; j < 12; j++) {
        x[j] = trn[j] + __shfl(Mv, (tid & 48) | j, 64);
        m = fmaxf(m, x[j]);
      }
      float ss = 0.f;
#pragma unroll
      for (int j = 0; j < 12; j++) ss += __expf(x[j] - m);
      Mv = fe[t * NTAGS + nn] + m + __logf(ss);
    }
    if (n < 12) Pc[ch * 144 + n * 12 + p] = Mv;
  }

  // partial gold score for this chunk (fe is read-only now)
  if (tid < 64) {
    float gp = 0.f;
#pragma unroll
    for (int b = 0; b < 2; b++) {
      const int tl = b * 64 + tid;
      const int t  = ch * CLEN + tl;
      const int tg = tags[t];
      const int pv = (t == 0) ? START : tags[t - 1];
      gp += trans[tg * 12 + pv] + fe[tl * NTAGS + tg];
    }
#pragma unroll
    for (int off = 32; off; off >>= 1) gp += __shfl_xor(gp, off, 64);
    if (tid == 0) Pg[ch] = gp;
  }
}

// ---------------- 4. combine chunk matrices + stop + gold -----------------------------
__global__ __launch_bounds__(64) void k_crf_final(const float* __restrict__ Pc,
                                                  const float* __restrict__ Pg,
                                                  const int* __restrict__ tags,
                                                  const float* __restrict__ trans,
                                                  float* __restrict__ out) {
  const int tid = threadIdx.x;
  const int nn  = (tid < 12) ? tid : 11;

  float fv = (tid == START) ? 0.f : -10000.f;
  for (int c = 0; c < CCH; c++) {
    float x[12], m = -1e30f;
#pragma unroll
    for (int j = 0; j < 12; j++) {
      x[j] = Pc[c * 144 + nn * 12 + j] + __shfl(fv, j, 64);
      m = fmaxf(m, x[j]);
    }
    float ss = 0.f;
#pragma unroll
    for (int j = 0; j < 12; j++) ss += __expf(x[j] - m);
    fv = m + __logf(ss);
  }
  const float v = fv + trans[STOP * 12 + nn];
  float xs[12], m = -1e30f;
#pragma unroll
  for (int j = 0; j < 12; j++) {
    xs[j] = __shfl(v, j, 64);
    m = fmaxf(m, xs[j]);
  }
  float ss = 0.f;
#pragma unroll
  for (int j = 0; j < 12; j++) ss += __expf(xs[j] - m);
  const float fwd = m + __logf(ss);

  float gp = (tid < CCH) ? Pg[tid] : 0.f;
#pragma unroll
  for (int off = 32; off; off >>= 1) gp += __shfl_xor(gp, off, 64);

  if (tid == 0) out[0] = fwd - (gp + trans[STOP * 12 + tags[SEQ - 1]]);
}

// -------------------------------------------------------------------------------------
extern "C" void kernel_launch(void* const* d_in, const int* in_sizes, int n_in,
                              void* d_out, int out_size, void* d_ws, size_t ws_size,
                              hipStream_t stream) {
  const int*   sentence = (const int*)  d_in[0];
  const int*   tags     = (const int*)  d_in[1];
  const float* embed    = (const float*)d_in[2];
  const float* Wih_f    = (const float*)d_in[3];
  const float* Whh_f    = (const float*)d_in[4];
  const float* bih_f    = (const float*)d_in[5];
  const float* bhh_f    = (const float*)d_in[6];
  const float* Wih_b    = (const float*)d_in[7];
  const float* Whh_b    = (const float*)d_in[8];
  const float* bih_b    = (const float*)d_in[9];
  const float* bhh_b    = (const float*)d_in[10];
  const float* W_out    = (const float*)d_in[11];
  const float* b_out    = (const float*)d_in[12];
  const float* h0       = (const float*)d_in[13];
  const float* c0       = (const float*)d_in[14];
  const float* trans    = (const float*)d_in[15];
  float* out = (float*)d_out;

  char* ws = (char*)d_ws;
  uint32_t* q4    = (uint32_t*)ws;                          // 512 KB
  float*    scales= (float*)(ws + (512l << 10));            // 8 KB
  float*    pre   = (float*)(ws + (1l  << 20));             // 16 MB : pre[2][2048][1024] interleaved
  float*    hs    = (float*)(ws + (17l << 20));             // 4 MB  : hs[2][2048][256]
  float*    Pc    = (float*)(ws + (21l << 20));             // 9 KB  : Pc[16][12][12]
  float*    Pg    = (float*)(ws + (21l << 20) + (16l<<10)); // 64 B  : Pg[16]

  k_prep<<<768, 256, 0, stream>>>(sentence, embed, Wih_f, bih_f, bhh_f,
                                  Wih_b, bih_b, bhh_b, Whh_f, Whh_b,
                                  q4, scales, pre);
  k_lstm<<<2, 1024, 0, stream>>>(q4, scales, pre, h0, c0, hs);
  k_crf_chunk<<<CCH, 192, 0, stream>>>(hs, W_out, b_out, trans, tags, Pc, Pg);
  k_crf_final<<<1, 64, 0, stream>>>(Pc, Pg, tags, trans, out);
}

// Round 6
// 2247.232 us; speedup vs baseline: 6.8960x; 1.0165x over previous
//
#include <hip/hip_runtime.h>
#include <hip/hip_bf16.h>
#include <stdint.h>

#define SEQ   2048
#define EMB   256
#define HHD   256      // per-direction hidden
#define GATES 1024     // 4*HHD
#define NTAGS 12
#define START 10
#define STOP  11
#define CCH   16       // CRF chunks
#define CLEN  128      // steps per chunk

__device__ __forceinline__ int sdot4(uint32_t a, uint32_t b, int c) {
#if __has_builtin(__builtin_amdgcn_sdot4)
  return __builtin_amdgcn_sdot4((int)a, (int)b, c, false);
#else
  int r = c;
#pragma unroll
  for (int i = 0; i < 4; i++) {
    int av = (int)(signed char)((a >> (8 * i)) & 255);
    int bv = (int)(signed char)((b >> (8 * i)) & 255);
    r += av * bv;
  }
  return r;
#endif
}

__device__ __forceinline__ float fsig(float x) {
  float e = __expf(-x);
  return __builtin_amdgcn_rcpf(1.0f + e);
}

__device__ __forceinline__ void sched_fence() {
#if __has_builtin(__builtin_amdgcn_sched_barrier)
  __builtin_amdgcn_sched_barrier(0);
#endif
}

// quad-level lane exchange via DPP (2-cyc VALU, replaces ~120-cyc ds_bpermute)
// quad_perm ctrl: xor1 = [1,0,3,2] = 0xB1 ; xor2 = [2,3,0,1] = 0x4E
__device__ __forceinline__ float qxor1(float x) {
#if __has_builtin(__builtin_amdgcn_update_dpp)
  int i = __builtin_bit_cast(int, x);
  i = __builtin_amdgcn_update_dpp(0, i, 0xB1, 0xF, 0xF, true);
  return __builtin_bit_cast(float, i);
#else
  return __shfl_xor(x, 1, 64);
#endif
}
__device__ __forceinline__ float qxor2(float x) {
#if __has_builtin(__builtin_amdgcn_update_dpp)
  int i = __builtin_bit_cast(int, x);
  i = __builtin_amdgcn_update_dpp(0, i, 0x4E, 0xF, 0xF, true);
  return __builtin_bit_cast(float, i);
#else
  return __shfl_xor(x, 2, 64);
#endif
}

// ---------------- 1. fused: input projection (blocks 0..255) + Whh quant (256..767) --
// proj writes pre[] GATE-INTERLEAVED: slot(t, row r) = (r&255)*4 + qmap[r>>8]
// quad order in k_lstm: pos0=i, pos1=g, pos2=f, pos3=o  ->  qmap(i,f,g,o) = {0,2,1,3}
__global__ __launch_bounds__(256) void k_prep(const int* __restrict__ sentence,
                                              const float* __restrict__ embed,
                                              const float* __restrict__ Wih_f,
                                              const float* __restrict__ bih_f,
                                              const float* __restrict__ bhh_f,
                                              const float* __restrict__ Wih_b,
                                              const float* __restrict__ bih_b,
                                              const float* __restrict__ bhh_b,
                                              const float* __restrict__ whh_f,
                                              const float* __restrict__ whh_b,
                                              uint32_t* __restrict__ q4,
                                              float* __restrict__ scales,
                                              float* __restrict__ pre) {
  const int tid = threadIdx.x;
  if (blockIdx.x >= 256) {
    // ---- quant part: one wave per gate-row ----
    const int idx  = (blockIdx.x - 256) * 256 + tid;
    const int row  = idx >> 6;          // 0..2047
    const int lane = tid & 63;
    const int d = row >> 10, r = row & 1023;
    const float4 w = *(const float4*)((d ? whh_b : whh_f) + (long)r * HHD + lane * 4);
    float m = fmaxf(fmaxf(fabsf(w.x), fabsf(w.y)), fmaxf(fabsf(w.z), fabsf(w.w)));
#pragma unroll
    for (int off = 32; off; off >>= 1) m = fmaxf(m, __shfl_xor(m, off, 64));
    m = fmaxf(m, 1e-20f);
    const float inv = 127.f / m;
    int a = (int)rintf(w.x * inv), b = (int)rintf(w.y * inv);
    int c = (int)rintf(w.z * inv), e = (int)rintf(w.w * inv);
    q4[row * 64 + lane] = (uint32_t)(a & 255) | ((uint32_t)(b & 255) << 8) |
                          ((uint32_t)(c & 255) << 16) | ((uint32_t)(e & 255) << 24);
    if (lane == 0) scales[row] = m / 127.f;
    return;
  }
  // ---- proj part: 16 timesteps per block ----
  const int dir = blockIdx.x >> 7;
  const int t0  = (blockIdx.x & 127) * 16;
  const float* Wih = dir ? Wih_b : Wih_f;
  const float* bih = dir ? bih_b : bih_f;
  const float* bhh = dir ? bhh_b : bhh_f;

  __shared__ float xs[16][256];
#pragma unroll
  for (int i = 0; i < 16; i++) {
    int s = sentence[t0 + i];
    xs[i][tid] = embed[(long)s * EMB + tid];
  }
  __syncthreads();

  const int r0 = tid * 4;
  float acc[4][16];
#pragma unroll
  for (int j = 0; j < 4; j++)
#pragma unroll
    for (int t = 0; t < 16; t++) acc[j][t] = 0.f;

  const float4* W4 = (const float4*)Wih;
  for (int kq = 0; kq < 64; kq++) {
    float4 w[4];
#pragma unroll
    for (int j = 0; j < 4; j++) w[j] = W4[(r0 + j) * 64 + kq];
#pragma unroll
    for (int t = 0; t < 16; t++) {
      float4 xv = ((const float4*)xs[t])[kq];
#pragma unroll
      for (int j = 0; j < 4; j++)
        acc[j][t] += w[j].x * xv.x + w[j].y * xv.y + w[j].z * xv.z + w[j].w * xv.w;
    }
  }
  const int glin = r0 >> 8;                              // gate index (i,f,g,o)
  const int qpos = (glin == 0) ? 0 : (glin == 1) ? 2 : (glin == 2) ? 1 : 3;
#pragma unroll
  for (int j = 0; j < 4; j++) {
    const int u = (r0 + j) & 255;
    float bsum = bih[r0 + j] + bhh[r0 + j];
#pragma unroll
    for (int t = 0; t < 16; t++)
      pre[((long)(dir * SEQ + t0 + t)) * GATES + u * 4 + qpos] = acc[j][t] + bsum;
  }
}

// ---------------- 2. sequential LSTM: 1 block/dir, 1024 thr, 1 gate-row per lane -----
// Lane L = 4u+g owns row {i:u, g:512+u, f:256+u, o:768+u}[g]. 64 weight dwords/lane,
// fully-unrolled static indexing. __launch_bounds__(1024,4): 4 waves/EU = exactly one
// block/CU -> 128-reg budget -> weights fit in ARCH VGPRs (R5's 64-reg target caused
// AGPR spill+shuttle). 4 accumulators break the sdot dep chain; DPP quad-perm replaces
// the two bpermute shuffles on the critical path.
__global__ __launch_bounds__(1024, 4) void k_lstm(const uint32_t* __restrict__ q4,
                                                  const float* __restrict__ scales,
                                                  const float* __restrict__ pre,
                                                  const float* __restrict__ h0,
                                                  const float* __restrict__ c0,
                                                  float* __restrict__ hs) {
  const int dir = blockIdx.x;
  const int L   = threadIdx.x;
  const int u   = L >> 2;
  const int g   = L & 3;

  __shared__ __align__(16) uint8_t hbuf[2][256];

  const int gbase = (g == 0) ? 0 : (g == 1) ? 512 : (g == 2) ? 256 : 768;
  const int row   = gbase + u;
  const long base = (long)dir * GATES;

  uint4 w[16];
  {
    const uint4* qq = (const uint4*)q4;
#pragma unroll
    for (int j = 0; j < 16; j++) w[j] = qq[(base + row) * 16 + j];
  }
  const float sc = scales[base + row];
  const float sc1 = sc * (1.f / 127.f);   // steady-state h scale
  const float sc0 = sc * (4.f / 127.f);   // step-0 h scale (h0 clamped at |4|)

  if (L < 256) {
    float v = h0[dir * HHD + L] * (127.f / 4.f);
    v = fminf(fmaxf(v, -127.f), 127.f);
    hbuf[0][L] = (uint8_t)(int)rintf(v);
  }
  float c_st = c0[dir * HHD + u];
  __syncthreads();

  const float* pd = pre + (long)dir * SEQ * GATES;
  float* hsd      = hs  + (long)dir * SEQ * HHD;

  const long dlt = dir ? -(long)GATES : (long)GATES;
  const float* pp = pd + (long)(dir ? SEQ - 1 : 0) * GATES + L;
  float nxt = *pp;

  const float gm  = (g == 1) ? 2.f : 1.f;   // tanh(x)=2*sig(2x)-1 for the g-gate
  const bool  is2 = (g & 2) != 0;           // lanes 2,3 hold f,o
  const bool  is3 = (g == 3);

  for (int s = 0; s < SEQ; s++) {
    const int t = dir ? (SEQ - 1 - s) : s;
    const float pre_v = nxt;
    if (s + 1 < SEQ) pp += dlt;
    nxt = *pp;                                // prefetch next step under the dots

    const uint4* hq4 = (const uint4*)hbuf[s & 1];
    int acc0 = 0, acc1 = 0, acc2 = 0, acc3 = 0;
    // 4 groups of (4 x ds_read_b128 -> 16 x sdot4); sched_barrier between groups
    // caps in-flight h registers so total pressure stays under the 128 cap.
#pragma unroll
    for (int blk = 0; blk < 4; blk++) {
      uint4 h0q = hq4[blk * 4 + 0];
      uint4 h1q = hq4[blk * 4 + 1];
      uint4 h2q = hq4[blk * 4 + 2];
      uint4 h3q = hq4[blk * 4 + 3];
      acc0 = sdot4(w[blk * 4 + 0].x, h0q.x, acc0);
      acc1 = sdot4(w[blk * 4 + 0].y, h0q.y, acc1);
      acc2 = sdot4(w[blk * 4 + 0].z, h0q.z, acc2);
      acc3 = sdot4(w[blk * 4 + 0].w, h0q.w, acc3);
      acc0 = sdot4(w[blk * 4 + 1].x, h1q.x, acc0);
      acc1 = sdot4(w[blk * 4 + 1].y, h1q.y, acc1);
      acc2 = sdot4(w[blk * 4 + 1].z, h1q.z, acc2);
      acc3 = sdot4(w[blk * 4 + 1].w, h1q.w, acc3);
      acc0 = sdot4(w[blk * 4 + 2].x, h2q.x, acc0);
      acc1 = sdot4(w[blk * 4 + 2].y, h2q.y, acc1);
      acc2 = sdot4(w[blk * 4 + 2].z, h2q.z, acc2);
      acc3 = sdot4(w[blk * 4 + 2].w, h2q.w, acc3);
      acc0 = sdot4(w[blk * 4 + 3].x, h3q.x, acc0);
      acc1 = sdot4(w[blk * 4 + 3].y, h3q.y, acc1);
      acc2 = sdot4(w[blk * 4 + 3].z, h3q.z, acc2);
      acc3 = sdot4(w[blk * 4 + 3].w, h3q.w, acc3);
      sched_fence();
    }
    const int   acc = (acc0 + acc1) + (acc2 + acc3);
    const float scs = (s == 0) ? sc0 : sc1;
    const float gv  = pre_v + scs * (float)acc;

    // activation: sig for i,f,o ; tanh for g (gm trick, divergence-free)
    const float x = fsig(gv * gm) * gm - (gm - 1.f);
    const float y = qxor1(x);                 // quad: 0<->1 (i,g), 2<->3 (f,o)
    const float a = is2 ? c_st : y;
    const float b = is3 ? y : x;
    const float q = b * a;                    // lanes0,1: i*g ; lanes2,3: f*c
    const float z = qxor2(q);
    const float c_new = q + z;                // identical on all 4 quad lanes
    c_st = c_new;

    const float th = 2.f * fsig(2.f * c_new) - 1.f;
    const float ho = is3 ? x : y;             // o on lanes 2,3
    const float hv = ho * th;

    if (g == 2) hbuf[(s + 1) & 1][u] = (uint8_t)(int)rintf(hv * 127.f);  // |hv|<1
    if (g == 3) hsd[(long)t * HHD + u] = hv;
    __syncthreads();
  }
}

// ---------------- 3. CRF chunk: compute feats for 128 steps, fold to 12x12, gold -----
__global__ __launch_bounds__(192) void k_crf_chunk(const float* __restrict__ hs,
                                                   const float* __restrict__ W_out,
                                                   const float* __restrict__ b_out,
                                                   const float* __restrict__ trans,
                                                   const int* __restrict__ tags,
                                                   float* __restrict__ Pc,
                                                   float* __restrict__ Pg) {
  const int ch  = blockIdx.x;
  const int tid = threadIdx.x;

  __shared__ float Wl[12 * 520];
  __shared__ float fe[CLEN * NTAGS];
  for (int i = tid; i < 12 * 512; i += 192) Wl[(i / 512) * 520 + (i % 512)] = W_out[i];
  __syncthreads();

  // feats: 16 t-slots x 12 tags; each thread does 8 timesteps
  {
    const int slot = tid / 12, n = tid % 12;
    const float bn = b_out[n];
    const float4* Wa = (const float4*)&Wl[n * 520];
    const float4* Wb = (const float4*)&Wl[n * 520 + 256];
    for (int k = 0; k < 8; k++) {
      const int tl = k * 16 + slot;
      const int t  = ch * CLEN + tl;
      const float4* hf4 = (const float4*)(hs + (long)t * HHD);
      const float4* hb4 = (const float4*)(hs + (long)SEQ * HHD + (long)t * HHD);
      float acc = bn;
#pragma unroll 8
      for (int j = 0; j < 64; j++) {
        float4 w = Wa[j], h = hf4[j];
        acc += w.x * h.x + w.y * h.y + w.z * h.z + w.w * h.w;
      }
#pragma unroll 8
      for (int j = 0; j < 64; j++) {
        float4 w = Wb[j], h = hb4[j];
        acc += w.x * h.x + w.y * h.y + w.z * h.z + w.w * h.w;
      }
      fe[tl * NTAGS + n] = acc;
    }
  }
  __syncthreads();

  // fold 128 steps into a 12x12 log-semiring matrix
  {
    const int n  = tid & 15;
    const int p  = tid >> 4;
    const int nn = (n < 12) ? n : 11;
    float trn[12];
#pragma unroll
    for (int j = 0; j < 12; j++) trn[j] = trans[nn * 12 + j];

    float Mv = trans[nn * 12 + p] + fe[nn];
    for (int t = 1; t < CLEN; t++) {
      float x[12], m = -1e30f;
#pragma unroll
      for (int j = 0; j < 12; j++) {
        x[j] = trn[j] + __shfl(Mv, (tid & 48) | j, 64);
        m = fmaxf(m, x[j]);
      }
      float ss = 0.f;
#pragma unroll
      for (int j = 0; j < 12; j++) ss += __expf(x[j] - m);
      Mv = fe[t * NTAGS + nn] + m + __logf(ss);
    }
    if (n < 12) Pc[ch * 144 + n * 12 + p] = Mv;
  }

  // partial gold score for this chunk (fe is read-only now)
  if (tid < 64) {
    float gp = 0.f;
#pragma unroll
    for (int b = 0; b < 2; b++) {
      const int tl = b * 64 + tid;
      const int t  = ch * CLEN + tl;
      const int tg = tags[t];
      const int pv = (t == 0) ? START : tags[t - 1];
      gp += trans[tg * 12 + pv] + fe[tl * NTAGS + tg];
    }
#pragma unroll
    for (int off = 32; off; off >>= 1) gp += __shfl_xor(gp, off, 64);
    if (tid == 0) Pg[ch] = gp;
  }
}

// ---------------- 4. combine chunk matrices + stop + gold -----------------------------
__global__ __launch_bounds__(64) void k_crf_final(const float* __restrict__ Pc,
                                                  const float* __restrict__ Pg,
                                                  const int* __restrict__ tags,
                                                  const float* __restrict__ trans,
                                                  float* __restrict__ out) {
  const int tid = threadIdx.x;
  const int nn  = (tid < 12) ? tid : 11;

  float fv = (tid == START) ? 0.f : -10000.f;
  for (int c = 0; c < CCH; c++) {
    float x[12], m = -1e30f;
#pragma unroll
    for (int j = 0; j < 12; j++) {
      x[j] = Pc[c * 144 + nn * 12 + j] + __shfl(fv, j, 64);
      m = fmaxf(m, x[j]);
    }
    float ss = 0.f;
#pragma unroll
    for (int j = 0; j < 12; j++) ss += __expf(x[j] - m);
    fv = m + __logf(ss);
  }
  const float v = fv + trans[STOP * 12 + nn];
  float xs[12], m = -1e30f;
#pragma unroll
  for (int j = 0; j < 12; j++) {
    xs[j] = __shfl(v, j, 64);
    m = fmaxf(m, xs[j]);
  }
  float ss = 0.f;
#pragma unroll
  for (int j = 0; j < 12; j++) ss += __expf(xs[j] - m);
  const float fwd = m + __logf(ss);

  float gp = (tid < CCH) ? Pg[tid] : 0.f;
#pragma unroll
  for (int off = 32; off; off >>= 1) gp += __shfl_xor(gp, off, 64);

  if (tid == 0) out[0] = fwd - (gp + trans[STOP * 12 + tags[SEQ - 1]]);
}

// -------------------------------------------------------------------------------------
extern "C" void kernel_launch(void* const* d_in, const int* in_sizes, int n_in,
                              void* d_out, int out_size, void* d_ws, size_t ws_size,
                              hipStream_t stream) {
  const int*   sentence = (const int*)  d_in[0];
  const int*   tags     = (const int*)  d_in[1];
  const float* embed    = (const float*)d_in[2];
  const float* Wih_f    = (const float*)d_in[3];
  const float* Whh_f    = (const float*)d_in[4];
  const float* bih_f    = (const float*)d_in[5];
  const float* bhh_f    = (const float*)d_in[6];
  const float* Wih_b    = (const float*)d_in[7];
  const float* Whh_b    = (const float*)d_in[8];
  const float* bih_b    = (const float*)d_in[9];
  const float* bhh_b    = (const float*)d_in[10];
  const float* W_out    = (const float*)d_in[11];
  const float* b_out    = (const float*)d_in[12];
  const float* h0       = (const float*)d_in[13];
  const float* c0       = (const float*)d_in[14];
  const float* trans    = (const float*)d_in[15];
  float* out = (float*)d_out;

  char* ws = (char*)d_ws;
  uint32_t* q4    = (uint32_t*)ws;                          // 512 KB
  float*    scales= (float*)(ws + (512l << 10));            // 8 KB
  float*    pre   = (float*)(ws + (1l  << 20));             // 16 MB : pre[2][2048][1024] interleaved
  float*    hs    = (float*)(ws + (17l << 20));             // 4 MB  : hs[2][2048][256]
  float*    Pc    = (float*)(ws + (21l << 20));             // 9 KB  : Pc[16][12][12]
  float*    Pg    = (float*)(ws + (21l << 20) + (16l<<10)); // 64 B  : Pg[16]

  k_prep<<<768, 256, 0, stream>>>(sentence, embed, Wih_f, bih_f, bhh_f,
                                  Wih_b, bih_b, bhh_b, Whh_f, Whh_b,
                                  q4, scales, pre);
  k_lstm<<<2, 1024, 0, stream>>>(q4, scales, pre, h0, c0, hs);
  k_crf_chunk<<<CCH, 192, 0, stream>>>(hs, W_out, b_out, trans, tags, Pc, Pg);
  k_crf_final<<<1, 64, 0, stream>>>(Pc, Pg, tags, trans, out);
}